// Round 7
// baseline (261.254 us; speedup 1.0000x reference)
//
#include <hip/hip_runtime.h>
#include <hip/hip_fp16.h>
#include <math.h>

#define NSEQ 4096
#define LFFT 8192
#define NT   512

// ---------- complex helpers ----------
__device__ __forceinline__ float2 cadd(float2 a, float2 b){ return make_float2(a.x+b.x, a.y+b.y); }
__device__ __forceinline__ float2 csub(float2 a, float2 b){ return make_float2(a.x-b.x, a.y-b.y); }
__device__ __forceinline__ float2 cmul(float2 a, float2 b){
  return make_float2(fmaf(a.x,b.x,-(a.y*b.y)), fmaf(a.x,b.y, a.y*b.x));
}
// a * conj(b)
__device__ __forceinline__ float2 cmulc(float2 a, float2 b){
  return make_float2(fmaf(a.x,b.x, a.y*b.y), fmaf(a.y,b.x,-(a.x*b.y)));
}
#define R8C 0.70710678118654752440f
__device__ __forceinline__ float2 mulW8p1(float2 z){ return make_float2(R8C*(z.x+z.y), R8C*(z.y-z.x)); }
__device__ __forceinline__ float2 mulW8p3(float2 z){ return make_float2(R8C*(z.y-z.x), -R8C*(z.x+z.y)); }
__device__ __forceinline__ float2 mulW8m1(float2 z){ return make_float2(R8C*(z.x-z.y), R8C*(z.x+z.y)); }
__device__ __forceinline__ float2 mulW8m3(float2 z){ return make_float2(-R8C*(z.x+z.y), R8C*(z.x-z.y)); }
__device__ __forceinline__ float2 mulmi(float2 z){ return make_float2( z.y, -z.x); }
__device__ __forceinline__ float2 mulpi(float2 z){ return make_float2(-z.y,  z.x); }

// fp32 (8B-elem) swizzle, used by afft_kernel only
__device__ __forceinline__ int swz(int p){ return p ^ ((p>>4)&15); }
// fp16 (4B-elem) swizzle for conv_kernel z (involution over 32-banks)
__device__ __forceinline__ int swz4(int p){ return p ^ ((p>>5)&31); }

// fp16 LDS accessors (compute in fp32, store half2)
__device__ __forceinline__ float2 ldz(const __half2* z, int p){
  return __half22float2(z[swz4(p)]);
}
__device__ __forceinline__ void stz(__half2* z, int p, float2 v){
  z[swz4(p)] = __float22half2_rn(v);
}

// W(k) = exp(-2*pi*i*k/8192), composed from two small tables (k < 8192)
__device__ __forceinline__ float2 twget(const float2* twHi, const float2* twLo, int k){
  return cmul(twHi[k>>6], twLo[k&63]);
}

__device__ __forceinline__ void init_tw(float2* twHi, float2* twLo){
  const float PI2 = 6.28318530717958647692f;
  int tid = threadIdx.x;
  if (tid < 128){
    float ang = -PI2 * (float)(tid*64) / (float)LFFT;
    float s, c; sincosf(ang, &s, &c);
    twHi[tid] = make_float2(c, s);
  } else if (tid < 192){
    int k = tid - 128;
    float ang = -PI2 * (float)k / (float)LFFT;
    float s, c; sincosf(ang, &s, &c);
    twLo[k] = make_float2(c, s);
  }
  __syncthreads();
}

// ---------- radix-8 butterfly cores ----------
struct F2x8 { float2 v0,v1,v2,v3,v4,v5,v6,v7; };

__device__ __forceinline__ F2x8 bfly8_fwd(F2x8 x){
  float2 e0=cadd(x.v0,x.v4), o0=csub(x.v0,x.v4);
  float2 e1=cadd(x.v1,x.v5), o1=csub(x.v1,x.v5);
  float2 e2=cadd(x.v2,x.v6), o2=csub(x.v2,x.v6);
  float2 e3=cadd(x.v3,x.v7), o3=csub(x.v3,x.v7);
  float2 ta=cadd(e0,e2), tb=csub(e0,e2);
  float2 tc=cadd(e1,e3), td=csub(e1,e3);
  F2x8 y;
  y.v0=cadd(ta,tc); y.v4=csub(ta,tc);
  y.v2=make_float2(tb.x+td.y, tb.y-td.x);   // tb - i*td
  y.v6=make_float2(tb.x-td.y, tb.y+td.x);   // tb + i*td
  o1 = mulW8p1(o1); o2 = mulmi(o2); o3 = mulW8p3(o3);
  float2 ua=cadd(o0,o2), ub=csub(o0,o2);
  float2 uc=cadd(o1,o3), ud=csub(o1,o3);
  y.v1=cadd(ua,uc); y.v5=csub(ua,uc);
  y.v3=make_float2(ub.x+ud.y, ub.y-ud.x);   // ub - i*ud
  y.v7=make_float2(ub.x-ud.y, ub.y+ud.x);   // ub + i*ud
  return y;
}

__device__ __forceinline__ F2x8 bfly8_inv(F2x8 x){
  float2 e0=cadd(x.v0,x.v4), o0=csub(x.v0,x.v4);
  float2 e1=cadd(x.v1,x.v5), o1=csub(x.v1,x.v5);
  float2 e2=cadd(x.v2,x.v6), o2=csub(x.v2,x.v6);
  float2 e3=cadd(x.v3,x.v7), o3=csub(x.v3,x.v7);
  float2 ta=cadd(e0,e2), tb=csub(e0,e2);
  float2 tc=cadd(e1,e3), td=csub(e1,e3);
  F2x8 y;
  y.v0=cadd(ta,tc); y.v4=csub(ta,tc);
  y.v2=make_float2(tb.x-td.y, tb.y+td.x);   // tb + i*td
  y.v6=make_float2(tb.x+td.y, tb.y-td.x);   // tb - i*td
  o1 = mulW8m1(o1); o2 = mulpi(o2); o3 = mulW8m3(o3);
  float2 ua=cadd(o0,o2), ub=csub(o0,o2);
  float2 uc=cadd(o1,o3), ud=csub(o1,o3);
  y.v1=cadd(ua,uc); y.v5=csub(ua,uc);
  y.v3=make_float2(ub.x-ud.y, ub.y+ud.x);   // ub + i*ud
  y.v7=make_float2(ub.x+ud.y, ub.y-ud.x);   // ub - i*ud
  return y;
}

// ================= fp32-LDS stages (afft_kernel) =================
template<int H>
__device__ __forceinline__ void fwd_r8(float2* z, const float2* twHi, const float2* twLo){
  constexpr int STEP = LFFT/(8*H);
  const int tid = threadIdx.x;
  #pragma unroll
  for (int r = 0; r < LFFT/8/NT; ++r){
    int i = r*NT + tid;
    int pos = i & (H-1);
    int base = ((i - pos) << 3) + pos;
    F2x8 x;
    x.v0 = z[swz(base)];     x.v1 = z[swz(base+H)];
    x.v2 = z[swz(base+2*H)]; x.v3 = z[swz(base+3*H)];
    x.v4 = z[swz(base+4*H)]; x.v5 = z[swz(base+5*H)];
    x.v6 = z[swz(base+6*H)]; x.v7 = z[swz(base+7*H)];
    F2x8 y = bfly8_fwd(x);
    z[swz(base)] = y.v0;
    if constexpr (H > 1){
      float2 w1 = twget(twHi,twLo, pos*STEP);
      float2 w2 = cmul(w1,w1);
      float2 w3 = cmul(w2,w1);
      float2 w4 = cmul(w2,w2);
      float2 w5 = cmul(w4,w1);
      float2 w6 = cmul(w4,w2);
      float2 w7 = cmul(w4,w3);
      z[swz(base+H)]   = cmul(y.v1,w1);
      z[swz(base+2*H)] = cmul(y.v2,w2);
      z[swz(base+3*H)] = cmul(y.v3,w3);
      z[swz(base+4*H)] = cmul(y.v4,w4);
      z[swz(base+5*H)] = cmul(y.v5,w5);
      z[swz(base+6*H)] = cmul(y.v6,w6);
      z[swz(base+7*H)] = cmul(y.v7,w7);
    } else {
      z[swz(base+H)]   = y.v1;
      z[swz(base+2*H)] = y.v2;
      z[swz(base+3*H)] = y.v3;
      z[swz(base+4*H)] = y.v4;
      z[swz(base+5*H)] = y.v5;
      z[swz(base+6*H)] = y.v6;
      z[swz(base+7*H)] = y.v7;
    }
  }
  __syncthreads();
}

// ================= fp16-LDS stages (conv_kernel) =================
template<int H>
__device__ __forceinline__ void fwd_r8_h(__half2* z, const float2* twHi, const float2* twLo){
  constexpr int STEP = LFFT/(8*H);
  const int tid = threadIdx.x;
  #pragma unroll
  for (int r = 0; r < LFFT/8/NT; ++r){
    int i = r*NT + tid;
    int pos = i & (H-1);
    int base = ((i - pos) << 3) + pos;
    F2x8 x;
    x.v0 = ldz(z,base);     x.v1 = ldz(z,base+H);
    x.v2 = ldz(z,base+2*H); x.v3 = ldz(z,base+3*H);
    x.v4 = ldz(z,base+4*H); x.v5 = ldz(z,base+5*H);
    x.v6 = ldz(z,base+6*H); x.v7 = ldz(z,base+7*H);
    F2x8 y = bfly8_fwd(x);
    stz(z,base, y.v0);
    float2 w1 = twget(twHi,twLo, pos*STEP);
    float2 w2 = cmul(w1,w1);
    float2 w3 = cmul(w2,w1);
    float2 w4 = cmul(w2,w2);
    float2 w5 = cmul(w4,w1);
    float2 w6 = cmul(w4,w2);
    float2 w7 = cmul(w4,w3);
    stz(z,base+H,   cmul(y.v1,w1));
    stz(z,base+2*H, cmul(y.v2,w2));
    stz(z,base+3*H, cmul(y.v3,w3));
    stz(z,base+4*H, cmul(y.v4,w4));
    stz(z,base+5*H, cmul(y.v5,w5));
    stz(z,base+6*H, cmul(y.v6,w6));
    stz(z,base+7*H, cmul(y.v7,w7));
  }
  __syncthreads();
}

// Last forward stage (H=1) fused with pointwise multiply by Ah (scrambled-linear layout).
__device__ __forceinline__ void fwd_r8_mulA_h(__half2* z, const float2* __restrict__ Ah){
  const int tid = threadIdx.x;
  #pragma unroll
  for (int r = 0; r < LFFT/8/NT; ++r){
    int i = r*NT + tid;
    int base = i << 3;
    F2x8 x;
    x.v0 = ldz(z,base);   x.v1 = ldz(z,base+1);
    x.v2 = ldz(z,base+2); x.v3 = ldz(z,base+3);
    x.v4 = ldz(z,base+4); x.v5 = ldz(z,base+5);
    x.v6 = ldz(z,base+6); x.v7 = ldz(z,base+7);
    F2x8 y = bfly8_fwd(x);
    stz(z,base,   cmul(y.v0, Ah[base]));
    stz(z,base+1, cmul(y.v1, Ah[base+1]));
    stz(z,base+2, cmul(y.v2, Ah[base+2]));
    stz(z,base+3, cmul(y.v3, Ah[base+3]));
    stz(z,base+4, cmul(y.v4, Ah[base+4]));
    stz(z,base+5, cmul(y.v5, Ah[base+5]));
    stz(z,base+6, cmul(y.v6, Ah[base+6]));
    stz(z,base+7, cmul(y.v7, Ah[base+7]));
  }
  __syncthreads();
}

// Inverse DIT stage (conjugate twiddles applied on inputs), mirrored order.
template<int H>
__device__ __forceinline__ void inv_r8_h(__half2* z, const float2* twHi, const float2* twLo){
  constexpr int STEP = LFFT/(8*H);
  const int tid = threadIdx.x;
  #pragma unroll
  for (int r = 0; r < LFFT/8/NT; ++r){
    int i = r*NT + tid;
    int pos = i & (H-1);
    int base = ((i - pos) << 3) + pos;
    F2x8 x;
    x.v0 = ldz(z,base);
    if constexpr (H > 1){
      float2 w1 = twget(twHi,twLo, pos*STEP);
      float2 w2 = cmul(w1,w1);
      float2 w3 = cmul(w2,w1);
      float2 w4 = cmul(w2,w2);
      float2 w5 = cmul(w4,w1);
      float2 w6 = cmul(w4,w2);
      float2 w7 = cmul(w4,w3);
      x.v1 = cmulc(ldz(z,base+H),   w1);
      x.v2 = cmulc(ldz(z,base+2*H), w2);
      x.v3 = cmulc(ldz(z,base+3*H), w3);
      x.v4 = cmulc(ldz(z,base+4*H), w4);
      x.v5 = cmulc(ldz(z,base+5*H), w5);
      x.v6 = cmulc(ldz(z,base+6*H), w6);
      x.v7 = cmulc(ldz(z,base+7*H), w7);
    } else {
      x.v1 = ldz(z,base+H);
      x.v2 = ldz(z,base+2*H);
      x.v3 = ldz(z,base+3*H);
      x.v4 = ldz(z,base+4*H);
      x.v5 = ldz(z,base+5*H);
      x.v6 = ldz(z,base+6*H);
      x.v7 = ldz(z,base+7*H);
    }
    F2x8 y = bfly8_inv(x);
    stz(z,base,     y.v0);
    stz(z,base+H,   y.v1);
    stz(z,base+2*H, y.v2);
    stz(z,base+3*H, y.v3);
    stz(z,base+4*H, y.v4);
    stz(z,base+5*H, y.v5);
    stz(z,base+6*H, y.v6);
    stz(z,base+7*H, y.v7);
  }
  __syncthreads();
}

// ---------- kernel A: DynamicPosBias MLP -> a[h][j] ----------
__device__ __forceinline__ void ln_relu16(const float* v, float* y, const float* g, const float* be){
  float mu = 0.f;
  #pragma unroll
  for (int p=0;p<16;++p) mu += v[p];
  mu *= (1.f/16.f);
  float var = 0.f;
  #pragma unroll
  for (int p=0;p<16;++p){ float d = v[p]-mu; var = fmaf(d,d,var); }
  var *= (1.f/16.f);
  float inv = 1.f / sqrtf(var + 1e-5f);
  #pragma unroll
  for (int p=0;p<16;++p){
    float t = fmaf((v[p]-mu)*inv, g[p], be[p]);
    y[p] = t > 0.f ? t : 0.f;
  }
}

__global__ void dpb_kernel(const float* __restrict__ W0, const float* __restrict__ b0,
                           const float* __restrict__ g1, const float* __restrict__ be1,
                           const float* __restrict__ W1, const float* __restrict__ b1,
                           const float* __restrict__ g2, const float* __restrict__ be2,
                           const float* __restrict__ W2, const float* __restrict__ b2,
                           const float* __restrict__ g3, const float* __restrict__ be3,
                           const float* __restrict__ W3, const float* __restrict__ b3,
                           float* __restrict__ a){
  int j = blockIdx.x*256 + threadIdx.x;   // 0..8191
  float t;
  if (j == 0 || j == NSEQ) t = 0.f;
  else if (j < NSEQ)       t = (float)j;
  else                     t = (float)(j - LFFT);   // negative side

  float v[16], y[16];
  #pragma unroll
  for (int p=0;p<16;++p) v[p] = fmaf(t, W0[p], b0[p]);
  ln_relu16(v, y, g1, be1);
  #pragma unroll
  for (int q=0;q<16;++q){ float s=b1[q];
    #pragma unroll
    for (int p=0;p<16;++p) s = fmaf(y[p], W1[p*16+q], s);
    v[q]=s; }
  ln_relu16(v, y, g2, be2);
  #pragma unroll
  for (int q=0;q<16;++q){ float s=b2[q];
    #pragma unroll
    for (int p=0;p<16;++p) s = fmaf(y[p], W2[p*16+q], s);
    v[q]=s; }
  ln_relu16(v, y, g3, be3);
  #pragma unroll
  for (int hh=0;hh<8;++hh){ float s=b3[hh];
    #pragma unroll
    for (int p=0;p<16;++p) s = fmaf(y[p], W3[p*8+hh], s);
    a[hh*LFFT + j] = s; }
}

// ---------- kernel B: forward FFT of a (per head), scrambled order, /L (fp32) ----------
__global__ __launch_bounds__(NT, 4) void afft_kernel(const float* __restrict__ a,
                                                     float2* __restrict__ Ahat){
  __shared__ float2 z[LFFT];
  __shared__ float2 twHi[128];
  __shared__ float2 twLo[64];
  init_tw(twHi, twLo);
  const int h = blockIdx.x, tid = threadIdx.x;
  const float* ah = a + h*LFFT;
  #pragma unroll
  for (int r = 0; r < LFFT/NT; ++r){
    int j = r*NT + tid;
    z[swz(j)] = make_float2(ah[j], 0.f);
  }
  __syncthreads();
  // radix-2 DIF stage, full length 8192
  #pragma unroll
  for (int r = 0; r < LFFT/2/NT; ++r){
    int i = r*NT + tid;
    float2 u = z[swz(i)], v = z[swz(i+NSEQ)];
    z[swz(i)]      = cadd(u, v);
    z[swz(i+NSEQ)] = cmul(csub(u, v), twget(twHi,twLo,i));
  }
  __syncthreads();
  fwd_r8<512>(z,twHi,twLo); fwd_r8<64>(z,twHi,twLo);
  fwd_r8<8>(z,twHi,twLo);   fwd_r8<1>(z,twHi,twLo);
  const float sc = 1.f/(float)LFFT;
  float2* Ah = Ahat + h*LFFT;
  #pragma unroll
  for (int r = 0; r < LFFT/NT; ++r){
    int p = r*NT + tid;
    float2 v = z[swz(p)];
    Ah[p] = make_float2(v.x*sc, v.y*sc);
  }
}

// ---------- kernel C: packed-pair FFT convolution (fp16 LDS) ----------
__global__ __launch_bounds__(NT, 8) void conv_kernel(const float* __restrict__ x,
                                                     const float2* __restrict__ Ahat,
                                                     float* __restrict__ out){
  __shared__ __half2 z[LFFT];          // 32 KB
  __shared__ float2 twHi[128];
  __shared__ float2 twLo[64];
  init_tw(twHi, twLo);

  // XCD-aware swizzle: 32 e-pair blocks of the same (b,h) land on one XCD
  int bid = blockIdx.x;                       // 0..2047
  int logical = (bid & 7)*256 + (bid >> 3);
  int bh   = logical >> 5;                    // 0..63  (b*8+h)
  int pair = logical & 31;                    // 0..31
  int h    = bh & 7;
  const int tid = threadIdx.x;

  // load two adjacent e-columns as one complex sequence; fuse first radix-2
  // stage (upper half is zero padding): z[i]=v, z[i+4096]=v*W^i
  const float2* xp = (const float2*)x + (size_t)bh*NSEQ*32 + pair;
  #pragma unroll
  for (int r = 0; r < NSEQ/NT; ++r){
    int s = r*NT + tid;
    float2 v = xp[(size_t)s*32];
    stz(z, s,      v);
    stz(z, s+NSEQ, cmul(v, twget(twHi,twLo,s)));
  }
  __syncthreads();

  fwd_r8_h<512>(z,twHi,twLo); fwd_r8_h<64>(z,twHi,twLo);
  fwd_r8_h<8>(z,twHi,twLo);

  // last fwd stage fused with spectrum multiply (scrambled order matches afft)
  fwd_r8_mulA_h(z, Ahat + h*LFFT);

  inv_r8_h<1>(z,twHi,twLo);   inv_r8_h<8>(z,twHi,twLo);
  inv_r8_h<64>(z,twHi,twLo);  inv_r8_h<512>(z,twHi,twLo);

  // final inverse radix-2 stage fused with the store (only low half needed)
  float2* op = (float2*)out + (size_t)bh*NSEQ*32 + pair;
  #pragma unroll
  for (int r = 0; r < NSEQ/NT; ++r){
    int i = r*NT + tid;
    float2 u = ldz(z, i);
    float2 v = cmulc(ldz(z, i+NSEQ), twget(twHi,twLo,i));
    op[(size_t)i*32] = cadd(u, v);
  }
}

// ---------- launch ----------
extern "C" void kernel_launch(void* const* d_in, const int* in_sizes, int n_in,
                              void* d_out, int out_size, void* d_ws, size_t ws_size,
                              hipStream_t stream){
  const float* x   = (const float*)d_in[0];
  const float* W0  = (const float*)d_in[1];
  const float* b0  = (const float*)d_in[2];
  const float* g1  = (const float*)d_in[3];
  const float* be1 = (const float*)d_in[4];
  const float* W1  = (const float*)d_in[5];
  const float* b1  = (const float*)d_in[6];
  const float* g2  = (const float*)d_in[7];
  const float* be2 = (const float*)d_in[8];
  const float* W2  = (const float*)d_in[9];
  const float* b2  = (const float*)d_in[10];
  const float* g3  = (const float*)d_in[11];
  const float* be3 = (const float*)d_in[12];
  const float* W3  = (const float*)d_in[13];
  const float* b3  = (const float*)d_in[14];

  float*  a    = (float*)d_ws;                                   // 8*8192 f32 = 256 KB
  float2* Ahat = (float2*)((char*)d_ws + (size_t)8*LFFT*sizeof(float)); // 8*8192 c64 = 512 KB
  float*  outp = (float*)d_out;

  dpb_kernel<<<LFFT/256, 256, 0, stream>>>(W0,b0,g1,be1,W1,b1,g2,be2,W2,b2,g3,be3,W3,b3, a);
  afft_kernel<<<8, NT, 0, stream>>>(a, Ahat);
  conv_kernel<<<2048, NT, 0, stream>>>(x, Ahat, outp);
}

// Round 8
// 130.186 us; speedup vs baseline: 2.0068x; 2.0068x over previous
//
#include <hip/hip_runtime.h>
#include <hip/hip_fp16.h>
#include <math.h>

#define NSEQ 4096
#define LFFT 8192
#define NT   512

// ---------- complex helpers ----------
__device__ __forceinline__ float2 cadd(float2 a, float2 b){ return make_float2(a.x+b.x, a.y+b.y); }
__device__ __forceinline__ float2 csub(float2 a, float2 b){ return make_float2(a.x-b.x, a.y-b.y); }
__device__ __forceinline__ float2 cmul(float2 a, float2 b){
  return make_float2(fmaf(a.x,b.x,-(a.y*b.y)), fmaf(a.x,b.y, a.y*b.x));
}
// a * conj(b)
__device__ __forceinline__ float2 cmulc(float2 a, float2 b){
  return make_float2(fmaf(a.x,b.x, a.y*b.y), fmaf(a.y,b.x,-(a.x*b.y)));
}
#define R8C 0.70710678118654752440f
__device__ __forceinline__ float2 mulW8p1(float2 z){ return make_float2(R8C*(z.x+z.y), R8C*(z.y-z.x)); }
__device__ __forceinline__ float2 mulW8p3(float2 z){ return make_float2(R8C*(z.y-z.x), -R8C*(z.x+z.y)); }
__device__ __forceinline__ float2 mulW8m1(float2 z){ return make_float2(R8C*(z.x-z.y), R8C*(z.x+z.y)); }
__device__ __forceinline__ float2 mulW8m3(float2 z){ return make_float2(-R8C*(z.x+z.y), R8C*(z.x-z.y)); }
__device__ __forceinline__ float2 mulmi(float2 z){ return make_float2( z.y, -z.x); }
__device__ __forceinline__ float2 mulpi(float2 z){ return make_float2(-z.y,  z.x); }

// fp32 (8B-elem) swizzle, used by afft_kernel only
__device__ __forceinline__ int swz(int p){ return p ^ ((p>>4)&15); }
// fp16 (4B-elem) swizzle for conv_kernel z (involution over 32-banks)
__device__ __forceinline__ int swz4(int p){ return p ^ ((p>>5)&31); }

// fp16 LDS accessors (compute in fp32, store half2)
__device__ __forceinline__ float2 ldz(const __half2* z, int p){
  return __half22float2(z[swz4(p)]);
}
__device__ __forceinline__ void stz(__half2* z, int p, float2 v){
  z[swz4(p)] = __float22half2_rn(v);
}

// W(k) = exp(-2*pi*i*k/8192), composed from two small tables (k < 8192)
__device__ __forceinline__ float2 twget(const float2* twHi, const float2* twLo, int k){
  return cmul(twHi[k>>6], twLo[k&63]);
}

__device__ __forceinline__ void init_tw(float2* twHi, float2* twLo){
  const float PI2 = 6.28318530717958647692f;
  int tid = threadIdx.x;
  if (tid < 128){
    float ang = -PI2 * (float)(tid*64) / (float)LFFT;
    float s, c; sincosf(ang, &s, &c);
    twHi[tid] = make_float2(c, s);
  } else if (tid < 192){
    int k = tid - 128;
    float ang = -PI2 * (float)k / (float)LFFT;
    float s, c; sincosf(ang, &s, &c);
    twLo[k] = make_float2(c, s);
  }
  __syncthreads();
}

// ---------- radix-8 butterfly cores ----------
struct F2x8 { float2 v0,v1,v2,v3,v4,v5,v6,v7; };

__device__ __forceinline__ F2x8 bfly8_fwd(F2x8 x){
  float2 e0=cadd(x.v0,x.v4), o0=csub(x.v0,x.v4);
  float2 e1=cadd(x.v1,x.v5), o1=csub(x.v1,x.v5);
  float2 e2=cadd(x.v2,x.v6), o2=csub(x.v2,x.v6);
  float2 e3=cadd(x.v3,x.v7), o3=csub(x.v3,x.v7);
  float2 ta=cadd(e0,e2), tb=csub(e0,e2);
  float2 tc=cadd(e1,e3), td=csub(e1,e3);
  F2x8 y;
  y.v0=cadd(ta,tc); y.v4=csub(ta,tc);
  y.v2=make_float2(tb.x+td.y, tb.y-td.x);   // tb - i*td
  y.v6=make_float2(tb.x-td.y, tb.y+td.x);   // tb + i*td
  o1 = mulW8p1(o1); o2 = mulmi(o2); o3 = mulW8p3(o3);
  float2 ua=cadd(o0,o2), ub=csub(o0,o2);
  float2 uc=cadd(o1,o3), ud=csub(o1,o3);
  y.v1=cadd(ua,uc); y.v5=csub(ua,uc);
  y.v3=make_float2(ub.x+ud.y, ub.y-ud.x);   // ub - i*ud
  y.v7=make_float2(ub.x-ud.y, ub.y+ud.x);   // ub + i*ud
  return y;
}

__device__ __forceinline__ F2x8 bfly8_inv(F2x8 x){
  float2 e0=cadd(x.v0,x.v4), o0=csub(x.v0,x.v4);
  float2 e1=cadd(x.v1,x.v5), o1=csub(x.v1,x.v5);
  float2 e2=cadd(x.v2,x.v6), o2=csub(x.v2,x.v6);
  float2 e3=cadd(x.v3,x.v7), o3=csub(x.v3,x.v7);
  float2 ta=cadd(e0,e2), tb=csub(e0,e2);
  float2 tc=cadd(e1,e3), td=csub(e1,e3);
  F2x8 y;
  y.v0=cadd(ta,tc); y.v4=csub(ta,tc);
  y.v2=make_float2(tb.x-td.y, tb.y+td.x);   // tb + i*td
  y.v6=make_float2(tb.x+td.y, tb.y-td.x);   // tb - i*td
  o1 = mulW8m1(o1); o2 = mulpi(o2); o3 = mulW8m3(o3);
  float2 ua=cadd(o0,o2), ub=csub(o0,o2);
  float2 uc=cadd(o1,o3), ud=csub(o1,o3);
  y.v1=cadd(ua,uc); y.v5=csub(ua,uc);
  y.v3=make_float2(ub.x-ud.y, ub.y+ud.x);   // ub + i*ud
  y.v7=make_float2(ub.x+ud.y, ub.y-ud.x);   // ub - i*ud
  return y;
}

// ================= fp32-LDS stages (afft_kernel) =================
template<int H>
__device__ __forceinline__ void fwd_r8(float2* z, const float2* twHi, const float2* twLo){
  constexpr int STEP = LFFT/(8*H);
  const int tid = threadIdx.x;
  #pragma unroll
  for (int r = 0; r < LFFT/8/NT; ++r){
    int i = r*NT + tid;
    int pos = i & (H-1);
    int base = ((i - pos) << 3) + pos;
    F2x8 x;
    x.v0 = z[swz(base)];     x.v1 = z[swz(base+H)];
    x.v2 = z[swz(base+2*H)]; x.v3 = z[swz(base+3*H)];
    x.v4 = z[swz(base+4*H)]; x.v5 = z[swz(base+5*H)];
    x.v6 = z[swz(base+6*H)]; x.v7 = z[swz(base+7*H)];
    F2x8 y = bfly8_fwd(x);
    z[swz(base)] = y.v0;
    if constexpr (H > 1){
      float2 w1 = twget(twHi,twLo, pos*STEP);
      float2 w2 = cmul(w1,w1);
      float2 w3 = cmul(w2,w1);
      float2 w4 = cmul(w2,w2);
      float2 w5 = cmul(w4,w1);
      float2 w6 = cmul(w4,w2);
      float2 w7 = cmul(w4,w3);
      z[swz(base+H)]   = cmul(y.v1,w1);
      z[swz(base+2*H)] = cmul(y.v2,w2);
      z[swz(base+3*H)] = cmul(y.v3,w3);
      z[swz(base+4*H)] = cmul(y.v4,w4);
      z[swz(base+5*H)] = cmul(y.v5,w5);
      z[swz(base+6*H)] = cmul(y.v6,w6);
      z[swz(base+7*H)] = cmul(y.v7,w7);
    } else {
      z[swz(base+H)]   = y.v1;
      z[swz(base+2*H)] = y.v2;
      z[swz(base+3*H)] = y.v3;
      z[swz(base+4*H)] = y.v4;
      z[swz(base+5*H)] = y.v5;
      z[swz(base+6*H)] = y.v6;
      z[swz(base+7*H)] = y.v7;
    }
  }
  __syncthreads();
}

// ================= fp16-LDS stages (conv_kernel) =================
template<int H>
__device__ __forceinline__ void fwd_r8_h(__half2* z, const float2* twHi, const float2* twLo){
  constexpr int STEP = LFFT/(8*H);
  const int tid = threadIdx.x;
  #pragma unroll
  for (int r = 0; r < LFFT/8/NT; ++r){
    int i = r*NT + tid;
    int pos = i & (H-1);
    int base = ((i - pos) << 3) + pos;
    F2x8 x;
    x.v0 = ldz(z,base);     x.v1 = ldz(z,base+H);
    x.v2 = ldz(z,base+2*H); x.v3 = ldz(z,base+3*H);
    x.v4 = ldz(z,base+4*H); x.v5 = ldz(z,base+5*H);
    x.v6 = ldz(z,base+6*H); x.v7 = ldz(z,base+7*H);
    F2x8 y = bfly8_fwd(x);
    stz(z,base, y.v0);
    float2 w1 = twget(twHi,twLo, pos*STEP);
    float2 w2 = cmul(w1,w1);
    float2 w3 = cmul(w2,w1);
    float2 w4 = cmul(w2,w2);
    float2 w5 = cmul(w4,w1);
    float2 w6 = cmul(w4,w2);
    float2 w7 = cmul(w4,w3);
    stz(z,base+H,   cmul(y.v1,w1));
    stz(z,base+2*H, cmul(y.v2,w2));
    stz(z,base+3*H, cmul(y.v3,w3));
    stz(z,base+4*H, cmul(y.v4,w4));
    stz(z,base+5*H, cmul(y.v5,w5));
    stz(z,base+6*H, cmul(y.v6,w6));
    stz(z,base+7*H, cmul(y.v7,w7));
  }
  __syncthreads();
}

// Last forward stage (H=1) fused with pointwise multiply by Ah (scrambled-linear layout).
__device__ __forceinline__ void fwd_r8_mulA_h(__half2* z, const float2* __restrict__ Ah){
  const int tid = threadIdx.x;
  #pragma unroll
  for (int r = 0; r < LFFT/8/NT; ++r){
    int i = r*NT + tid;
    int base = i << 3;
    F2x8 x;
    x.v0 = ldz(z,base);   x.v1 = ldz(z,base+1);
    x.v2 = ldz(z,base+2); x.v3 = ldz(z,base+3);
    x.v4 = ldz(z,base+4); x.v5 = ldz(z,base+5);
    x.v6 = ldz(z,base+6); x.v7 = ldz(z,base+7);
    F2x8 y = bfly8_fwd(x);
    stz(z,base,   cmul(y.v0, Ah[base]));
    stz(z,base+1, cmul(y.v1, Ah[base+1]));
    stz(z,base+2, cmul(y.v2, Ah[base+2]));
    stz(z,base+3, cmul(y.v3, Ah[base+3]));
    stz(z,base+4, cmul(y.v4, Ah[base+4]));
    stz(z,base+5, cmul(y.v5, Ah[base+5]));
    stz(z,base+6, cmul(y.v6, Ah[base+6]));
    stz(z,base+7, cmul(y.v7, Ah[base+7]));
  }
  __syncthreads();
}

// Inverse DIT stage (conjugate twiddles applied on inputs), mirrored order.
template<int H>
__device__ __forceinline__ void inv_r8_h(__half2* z, const float2* twHi, const float2* twLo){
  constexpr int STEP = LFFT/(8*H);
  const int tid = threadIdx.x;
  #pragma unroll
  for (int r = 0; r < LFFT/8/NT; ++r){
    int i = r*NT + tid;
    int pos = i & (H-1);
    int base = ((i - pos) << 3) + pos;
    F2x8 x;
    x.v0 = ldz(z,base);
    if constexpr (H > 1){
      float2 w1 = twget(twHi,twLo, pos*STEP);
      float2 w2 = cmul(w1,w1);
      float2 w3 = cmul(w2,w1);
      float2 w4 = cmul(w2,w2);
      float2 w5 = cmul(w4,w1);
      float2 w6 = cmul(w4,w2);
      float2 w7 = cmul(w4,w3);
      x.v1 = cmulc(ldz(z,base+H),   w1);
      x.v2 = cmulc(ldz(z,base+2*H), w2);
      x.v3 = cmulc(ldz(z,base+3*H), w3);
      x.v4 = cmulc(ldz(z,base+4*H), w4);
      x.v5 = cmulc(ldz(z,base+5*H), w5);
      x.v6 = cmulc(ldz(z,base+6*H), w6);
      x.v7 = cmulc(ldz(z,base+7*H), w7);
    } else {
      x.v1 = ldz(z,base+H);
      x.v2 = ldz(z,base+2*H);
      x.v3 = ldz(z,base+3*H);
      x.v4 = ldz(z,base+4*H);
      x.v5 = ldz(z,base+5*H);
      x.v6 = ldz(z,base+6*H);
      x.v7 = ldz(z,base+7*H);
    }
    F2x8 y = bfly8_inv(x);
    stz(z,base,     y.v0);
    stz(z,base+H,   y.v1);
    stz(z,base+2*H, y.v2);
    stz(z,base+3*H, y.v3);
    stz(z,base+4*H, y.v4);
    stz(z,base+5*H, y.v5);
    stz(z,base+6*H, y.v6);
    stz(z,base+7*H, y.v7);
  }
  __syncthreads();
}

// ---------- kernel A: DynamicPosBias MLP -> a[h][j] ----------
__device__ __forceinline__ void ln_relu16(const float* v, float* y, const float* g, const float* be){
  float mu = 0.f;
  #pragma unroll
  for (int p=0;p<16;++p) mu += v[p];
  mu *= (1.f/16.f);
  float var = 0.f;
  #pragma unroll
  for (int p=0;p<16;++p){ float d = v[p]-mu; var = fmaf(d,d,var); }
  var *= (1.f/16.f);
  float inv = 1.f / sqrtf(var + 1e-5f);
  #pragma unroll
  for (int p=0;p<16;++p){
    float t = fmaf((v[p]-mu)*inv, g[p], be[p]);
    y[p] = t > 0.f ? t : 0.f;
  }
}

__global__ void dpb_kernel(const float* __restrict__ W0, const float* __restrict__ b0,
                           const float* __restrict__ g1, const float* __restrict__ be1,
                           const float* __restrict__ W1, const float* __restrict__ b1,
                           const float* __restrict__ g2, const float* __restrict__ be2,
                           const float* __restrict__ W2, const float* __restrict__ b2,
                           const float* __restrict__ g3, const float* __restrict__ be3,
                           const float* __restrict__ W3, const float* __restrict__ b3,
                           float* __restrict__ a){
  int j = blockIdx.x*256 + threadIdx.x;   // 0..8191
  float t;
  if (j == 0 || j == NSEQ) t = 0.f;
  else if (j < NSEQ)       t = (float)j;
  else                     t = (float)(j - LFFT);   // negative side

  float v[16], y[16];
  #pragma unroll
  for (int p=0;p<16;++p) v[p] = fmaf(t, W0[p], b0[p]);
  ln_relu16(v, y, g1, be1);
  #pragma unroll
  for (int q=0;q<16;++q){ float s=b1[q];
    #pragma unroll
    for (int p=0;p<16;++p) s = fmaf(y[p], W1[p*16+q], s);
    v[q]=s; }
  ln_relu16(v, y, g2, be2);
  #pragma unroll
  for (int q=0;q<16;++q){ float s=b2[q];
    #pragma unroll
    for (int p=0;p<16;++p) s = fmaf(y[p], W2[p*16+q], s);
    v[q]=s; }
  ln_relu16(v, y, g3, be3);
  #pragma unroll
  for (int hh=0;hh<8;++hh){ float s=b3[hh];
    #pragma unroll
    for (int p=0;p<16;++p) s = fmaf(y[p], W3[p*8+hh], s);
    a[hh*LFFT + j] = s; }
}

// ---------- kernel B: forward FFT of a (per head), scrambled order, /L (fp32) ----------
__global__ __launch_bounds__(NT, 4) void afft_kernel(const float* __restrict__ a,
                                                     float2* __restrict__ Ahat){
  __shared__ float2 z[LFFT];
  __shared__ float2 twHi[128];
  __shared__ float2 twLo[64];
  init_tw(twHi, twLo);
  const int h = blockIdx.x, tid = threadIdx.x;
  const float* ah = a + h*LFFT;
  #pragma unroll
  for (int r = 0; r < LFFT/NT; ++r){
    int j = r*NT + tid;
    z[swz(j)] = make_float2(ah[j], 0.f);
  }
  __syncthreads();
  // radix-2 DIF stage, full length 8192
  #pragma unroll
  for (int r = 0; r < LFFT/2/NT; ++r){
    int i = r*NT + tid;
    float2 u = z[swz(i)], v = z[swz(i+NSEQ)];
    z[swz(i)]      = cadd(u, v);
    z[swz(i+NSEQ)] = cmul(csub(u, v), twget(twHi,twLo,i));
  }
  __syncthreads();
  fwd_r8<512>(z,twHi,twLo); fwd_r8<64>(z,twHi,twLo);
  fwd_r8<8>(z,twHi,twLo);   fwd_r8<1>(z,twHi,twLo);
  const float sc = 1.f/(float)LFFT;
  float2* Ah = Ahat + h*LFFT;
  #pragma unroll
  for (int r = 0; r < LFFT/NT; ++r){
    int p = r*NT + tid;
    float2 v = z[swz(p)];
    Ah[p] = make_float2(v.x*sc, v.y*sc);
  }
}

// ---------- kernel C: packed-pair FFT convolution (fp16 LDS) ----------
// launch_bounds (NT,4): VGPR cap 128. The butterfly needs ~64 VGPRs; caps of
// 32 (rounds 3 & 7) spill to scratch and quadruple hbm_bytes. At <=64 VGPR the
// limiter is LDS (34 KB -> 4 blocks/CU = 32 waves/CU).
__global__ __launch_bounds__(NT, 4) void conv_kernel(const float* __restrict__ x,
                                                     const float2* __restrict__ Ahat,
                                                     float* __restrict__ out){
  __shared__ __half2 z[LFFT];          // 32 KB
  __shared__ float2 twHi[128];
  __shared__ float2 twLo[64];
  init_tw(twHi, twLo);

  // XCD-aware swizzle: 32 e-pair blocks of the same (b,h) land on one XCD
  int bid = blockIdx.x;                       // 0..2047
  int logical = (bid & 7)*256 + (bid >> 3);
  int bh   = logical >> 5;                    // 0..63  (b*8+h)
  int pair = logical & 31;                    // 0..31
  int h    = bh & 7;
  const int tid = threadIdx.x;

  // load two adjacent e-columns as one complex sequence; fuse first radix-2
  // stage (upper half is zero padding): z[i]=v, z[i+4096]=v*W^i
  const float2* xp = (const float2*)x + (size_t)bh*NSEQ*32 + pair;
  #pragma unroll
  for (int r = 0; r < NSEQ/NT; ++r){
    int s = r*NT + tid;
    float2 v = xp[(size_t)s*32];
    stz(z, s,      v);
    stz(z, s+NSEQ, cmul(v, twget(twHi,twLo,s)));
  }
  __syncthreads();

  fwd_r8_h<512>(z,twHi,twLo); fwd_r8_h<64>(z,twHi,twLo);
  fwd_r8_h<8>(z,twHi,twLo);

  // last fwd stage fused with spectrum multiply (scrambled order matches afft)
  fwd_r8_mulA_h(z, Ahat + h*LFFT);

  inv_r8_h<1>(z,twHi,twLo);   inv_r8_h<8>(z,twHi,twLo);
  inv_r8_h<64>(z,twHi,twLo);  inv_r8_h<512>(z,twHi,twLo);

  // final inverse radix-2 stage fused with the store (only low half needed)
  float2* op = (float2*)out + (size_t)bh*NSEQ*32 + pair;
  #pragma unroll
  for (int r = 0; r < NSEQ/NT; ++r){
    int i = r*NT + tid;
    float2 u = ldz(z, i);
    float2 v = cmulc(ldz(z, i+NSEQ), twget(twHi,twLo,i));
    op[(size_t)i*32] = cadd(u, v);
  }
}

// ---------- launch ----------
extern "C" void kernel_launch(void* const* d_in, const int* in_sizes, int n_in,
                              void* d_out, int out_size, void* d_ws, size_t ws_size,
                              hipStream_t stream){
  const float* x   = (const float*)d_in[0];
  const float* W0  = (const float*)d_in[1];
  const float* b0  = (const float*)d_in[2];
  const float* g1  = (const float*)d_in[3];
  const float* be1 = (const float*)d_in[4];
  const float* W1  = (const float*)d_in[5];
  const float* b1  = (const float*)d_in[6];
  const float* g2  = (const float*)d_in[7];
  const float* be2 = (const float*)d_in[8];
  const float* W2  = (const float*)d_in[9];
  const float* b2  = (const float*)d_in[10];
  const float* g3  = (const float*)d_in[11];
  const float* be3 = (const float*)d_in[12];
  const float* W3  = (const float*)d_in[13];
  const float* b3  = (const float*)d_in[14];

  float*  a    = (float*)d_ws;                                   // 8*8192 f32 = 256 KB
  float2* Ahat = (float2*)((char*)d_ws + (size_t)8*LFFT*sizeof(float)); // 8*8192 c64 = 512 KB
  float*  outp = (float*)d_out;

  dpb_kernel<<<LFFT/256, 256, 0, stream>>>(W0,b0,g1,be1,W1,b1,g2,be2,W2,b2,g3,be3,W3,b3, a);
  afft_kernel<<<8, NT, 0, stream>>>(a, Ahat);
  conv_kernel<<<2048, NT, 0, stream>>>(x, Ahat, outp);
}

// Round 9
// 113.228 us; speedup vs baseline: 2.3073x; 1.1498x over previous
//
#include <hip/hip_runtime.h>
#include <math.h>

#define NSEQ 4096
#define LFFT 8192
#define NT   512

// ---------- complex helpers ----------
__device__ __forceinline__ float2 cadd(float2 a, float2 b){ return make_float2(a.x+b.x, a.y+b.y); }
__device__ __forceinline__ float2 csub(float2 a, float2 b){ return make_float2(a.x-b.x, a.y-b.y); }
__device__ __forceinline__ float2 cmul(float2 a, float2 b){
  return make_float2(fmaf(a.x,b.x,-(a.y*b.y)), fmaf(a.x,b.y, a.y*b.x));
}
// a * conj(b)
__device__ __forceinline__ float2 cmulc(float2 a, float2 b){
  return make_float2(fmaf(a.x,b.x, a.y*b.y), fmaf(a.y,b.x,-(a.x*b.y)));
}
#define R8C 0.70710678118654752440f
__device__ __forceinline__ float2 mulW8p1(float2 z){ return make_float2(R8C*(z.x+z.y), R8C*(z.y-z.x)); }
__device__ __forceinline__ float2 mulW8p3(float2 z){ return make_float2(R8C*(z.y-z.x), -R8C*(z.x+z.y)); }
__device__ __forceinline__ float2 mulW8m1(float2 z){ return make_float2(R8C*(z.x-z.y), R8C*(z.x+z.y)); }
__device__ __forceinline__ float2 mulW8m3(float2 z){ return make_float2(-R8C*(z.x+z.y), R8C*(z.x-z.y)); }
__device__ __forceinline__ float2 mulmi(float2 z){ return make_float2( z.y, -z.x); }
__device__ __forceinline__ float2 mulpi(float2 z){ return make_float2(-z.y,  z.x); }

// LDS swizzle on float2 index. GF(2)-LINEAR: swz(a^b)=swz(a)^swz(b).
// For all stage patterns base+k*H == base|k*H (k-bits are zero in base), so
// swz(base+k*H) = swz(base) ^ swz(k*H)  with swz(k*H) a compile-time constant.
__device__ __host__ __forceinline__ constexpr int swz(int p){ return p ^ ((p>>4)&15); }

// W(k) = exp(-2*pi*i*k/8192), composed from two small tables (k < 8192)
__device__ __forceinline__ float2 twget(const float2* twHi, const float2* twLo, int k){
  return cmul(twHi[k>>6], twLo[k&63]);
}

__device__ __forceinline__ void init_tw(float2* twHi, float2* twLo){
  const float PI2 = 6.28318530717958647692f;
  int tid = threadIdx.x;
  if (tid < 128){
    float ang = -PI2 * (float)(tid*64) / (float)LFFT;
    float s, c; sincosf(ang, &s, &c);
    twHi[tid] = make_float2(c, s);
  } else if (tid < 192){
    int k = tid - 128;
    float ang = -PI2 * (float)k / (float)LFFT;
    float s, c; sincosf(ang, &s, &c);
    twLo[k] = make_float2(c, s);
  }
  __syncthreads();
}

// ---------- radix-8 butterfly cores ----------
struct F2x8 { float2 v0,v1,v2,v3,v4,v5,v6,v7; };

__device__ __forceinline__ F2x8 bfly8_fwd(F2x8 x){
  float2 e0=cadd(x.v0,x.v4), o0=csub(x.v0,x.v4);
  float2 e1=cadd(x.v1,x.v5), o1=csub(x.v1,x.v5);
  float2 e2=cadd(x.v2,x.v6), o2=csub(x.v2,x.v6);
  float2 e3=cadd(x.v3,x.v7), o3=csub(x.v3,x.v7);
  float2 ta=cadd(e0,e2), tb=csub(e0,e2);
  float2 tc=cadd(e1,e3), td=csub(e1,e3);
  F2x8 y;
  y.v0=cadd(ta,tc); y.v4=csub(ta,tc);
  y.v2=make_float2(tb.x+td.y, tb.y-td.x);   // tb - i*td
  y.v6=make_float2(tb.x-td.y, tb.y+td.x);   // tb + i*td
  o1 = mulW8p1(o1); o2 = mulmi(o2); o3 = mulW8p3(o3);
  float2 ua=cadd(o0,o2), ub=csub(o0,o2);
  float2 uc=cadd(o1,o3), ud=csub(o1,o3);
  y.v1=cadd(ua,uc); y.v5=csub(ua,uc);
  y.v3=make_float2(ub.x+ud.y, ub.y-ud.x);   // ub - i*ud
  y.v7=make_float2(ub.x-ud.y, ub.y+ud.x);   // ub + i*ud
  return y;
}

__device__ __forceinline__ F2x8 bfly8_inv(F2x8 x){
  float2 e0=cadd(x.v0,x.v4), o0=csub(x.v0,x.v4);
  float2 e1=cadd(x.v1,x.v5), o1=csub(x.v1,x.v5);
  float2 e2=cadd(x.v2,x.v6), o2=csub(x.v2,x.v6);
  float2 e3=cadd(x.v3,x.v7), o3=csub(x.v3,x.v7);
  float2 ta=cadd(e0,e2), tb=csub(e0,e2);
  float2 tc=cadd(e1,e3), td=csub(e1,e3);
  F2x8 y;
  y.v0=cadd(ta,tc); y.v4=csub(ta,tc);
  y.v2=make_float2(tb.x-td.y, tb.y+td.x);   // tb + i*td
  y.v6=make_float2(tb.x+td.y, tb.y-td.x);   // tb - i*td
  o1 = mulW8m1(o1); o2 = mulpi(o2); o3 = mulW8m3(o3);
  float2 ua=cadd(o0,o2), ub=csub(o0,o2);
  float2 uc=cadd(o1,o3), ud=csub(o1,o3);
  y.v1=cadd(ua,uc); y.v5=csub(ua,uc);
  y.v3=make_float2(ub.x-ud.y, ub.y+ud.x);   // ub + i*ud
  y.v7=make_float2(ub.x+ud.y, ub.y-ud.x);   // ub - i*ud
  return y;
}

// Forward DIF stage, sub-FFT length 8H. XOR-constant addressing. Tree twiddles.
template<int H>
__device__ __forceinline__ void fwd_r8(float2* z, const float2* twHi, const float2* twLo){
  constexpr int STEP = LFFT/(8*H);
  constexpr int O1=swz(1*H), O2=swz(2*H), O3=swz(3*H), O4=swz(4*H),
                O5=swz(5*H), O6=swz(6*H), O7=swz(7*H);
  const int tid = threadIdx.x;
  #pragma unroll
  for (int r = 0; r < LFFT/8/NT; ++r){
    int i = r*NT + tid;
    int pos = i & (H-1);
    int base = ((i - pos) << 3) + pos;
    int s = swz(base);
    F2x8 x;
    x.v0 = z[s];      x.v1 = z[s ^ O1];
    x.v2 = z[s ^ O2]; x.v3 = z[s ^ O3];
    x.v4 = z[s ^ O4]; x.v5 = z[s ^ O5];
    x.v6 = z[s ^ O6]; x.v7 = z[s ^ O7];
    F2x8 y = bfly8_fwd(x);
    z[s] = y.v0;
    if constexpr (H > 1){
      float2 w1 = twget(twHi,twLo, pos*STEP);
      float2 w2 = cmul(w1,w1);
      float2 w3 = cmul(w2,w1);
      float2 w4 = cmul(w2,w2);
      float2 w5 = cmul(w4,w1);
      float2 w6 = cmul(w4,w2);
      float2 w7 = cmul(w4,w3);
      z[s ^ O1] = cmul(y.v1,w1);
      z[s ^ O2] = cmul(y.v2,w2);
      z[s ^ O3] = cmul(y.v3,w3);
      z[s ^ O4] = cmul(y.v4,w4);
      z[s ^ O5] = cmul(y.v5,w5);
      z[s ^ O6] = cmul(y.v6,w6);
      z[s ^ O7] = cmul(y.v7,w7);
    } else {
      z[s ^ O1] = y.v1;
      z[s ^ O2] = y.v2;
      z[s ^ O3] = y.v3;
      z[s ^ O4] = y.v4;
      z[s ^ O5] = y.v5;
      z[s ^ O6] = y.v6;
      z[s ^ O7] = y.v7;
    }
  }
  __syncthreads();
}

// Last forward stage (H=1) fused with pointwise multiply by Ah (scrambled-linear layout).
__device__ __forceinline__ void fwd_r8_mulA(float2* z, const float2* __restrict__ Ah){
  const int tid = threadIdx.x;
  #pragma unroll
  for (int r = 0; r < LFFT/8/NT; ++r){
    int i = r*NT + tid;
    int base = i << 3;           // 8-aligned; swz(k)=k for k<8
    int s = swz(base);
    F2x8 x;
    x.v0 = z[s];     x.v1 = z[s ^ 1];
    x.v2 = z[s ^ 2]; x.v3 = z[s ^ 3];
    x.v4 = z[s ^ 4]; x.v5 = z[s ^ 5];
    x.v6 = z[s ^ 6]; x.v7 = z[s ^ 7];
    F2x8 y = bfly8_fwd(x);
    z[s]     = cmul(y.v0, Ah[base]);
    z[s ^ 1] = cmul(y.v1, Ah[base+1]);
    z[s ^ 2] = cmul(y.v2, Ah[base+2]);
    z[s ^ 3] = cmul(y.v3, Ah[base+3]);
    z[s ^ 4] = cmul(y.v4, Ah[base+4]);
    z[s ^ 5] = cmul(y.v5, Ah[base+5]);
    z[s ^ 6] = cmul(y.v6, Ah[base+6]);
    z[s ^ 7] = cmul(y.v7, Ah[base+7]);
  }
  __syncthreads();
}

// Inverse DIT stage (conjugate twiddles applied on inputs), mirrored order.
template<int H>
__device__ __forceinline__ void inv_r8(float2* z, const float2* twHi, const float2* twLo){
  constexpr int STEP = LFFT/(8*H);
  constexpr int O1=swz(1*H), O2=swz(2*H), O3=swz(3*H), O4=swz(4*H),
                O5=swz(5*H), O6=swz(6*H), O7=swz(7*H);
  const int tid = threadIdx.x;
  #pragma unroll
  for (int r = 0; r < LFFT/8/NT; ++r){
    int i = r*NT + tid;
    int pos = i & (H-1);
    int base = ((i - pos) << 3) + pos;
    int s = swz(base);
    F2x8 x;
    x.v0 = z[s];
    if constexpr (H > 1){
      float2 w1 = twget(twHi,twLo, pos*STEP);
      float2 w2 = cmul(w1,w1);
      float2 w3 = cmul(w2,w1);
      float2 w4 = cmul(w2,w2);
      float2 w5 = cmul(w4,w1);
      float2 w6 = cmul(w4,w2);
      float2 w7 = cmul(w4,w3);
      x.v1 = cmulc(z[s ^ O1], w1);
      x.v2 = cmulc(z[s ^ O2], w2);
      x.v3 = cmulc(z[s ^ O3], w3);
      x.v4 = cmulc(z[s ^ O4], w4);
      x.v5 = cmulc(z[s ^ O5], w5);
      x.v6 = cmulc(z[s ^ O6], w6);
      x.v7 = cmulc(z[s ^ O7], w7);
    } else {
      x.v1 = z[s ^ O1];
      x.v2 = z[s ^ O2];
      x.v3 = z[s ^ O3];
      x.v4 = z[s ^ O4];
      x.v5 = z[s ^ O5];
      x.v6 = z[s ^ O6];
      x.v7 = z[s ^ O7];
    }
    F2x8 y = bfly8_inv(x);
    z[s]      = y.v0;
    z[s ^ O1] = y.v1;
    z[s ^ O2] = y.v2;
    z[s ^ O3] = y.v3;
    z[s ^ O4] = y.v4;
    z[s ^ O5] = y.v5;
    z[s ^ O6] = y.v6;
    z[s ^ O7] = y.v7;
  }
  __syncthreads();
}

// ---------- kernel A: DynamicPosBias MLP -> a[h][j] ----------
__device__ __forceinline__ void ln_relu16(const float* v, float* y, const float* g, const float* be){
  float mu = 0.f;
  #pragma unroll
  for (int p=0;p<16;++p) mu += v[p];
  mu *= (1.f/16.f);
  float var = 0.f;
  #pragma unroll
  for (int p=0;p<16;++p){ float d = v[p]-mu; var = fmaf(d,d,var); }
  var *= (1.f/16.f);
  float inv = 1.f / sqrtf(var + 1e-5f);
  #pragma unroll
  for (int p=0;p<16;++p){
    float t = fmaf((v[p]-mu)*inv, g[p], be[p]);
    y[p] = t > 0.f ? t : 0.f;
  }
}

__global__ void dpb_kernel(const float* __restrict__ W0, const float* __restrict__ b0,
                           const float* __restrict__ g1, const float* __restrict__ be1,
                           const float* __restrict__ W1, const float* __restrict__ b1,
                           const float* __restrict__ g2, const float* __restrict__ be2,
                           const float* __restrict__ W2, const float* __restrict__ b2,
                           const float* __restrict__ g3, const float* __restrict__ be3,
                           const float* __restrict__ W3, const float* __restrict__ b3,
                           float* __restrict__ a){
  int j = blockIdx.x*256 + threadIdx.x;   // 0..8191
  float t;
  if (j == 0 || j == NSEQ) t = 0.f;
  else if (j < NSEQ)       t = (float)j;
  else                     t = (float)(j - LFFT);   // negative side

  float v[16], y[16];
  #pragma unroll
  for (int p=0;p<16;++p) v[p] = fmaf(t, W0[p], b0[p]);
  ln_relu16(v, y, g1, be1);
  #pragma unroll
  for (int q=0;q<16;++q){ float s=b1[q];
    #pragma unroll
    for (int p=0;p<16;++p) s = fmaf(y[p], W1[p*16+q], s);
    v[q]=s; }
  ln_relu16(v, y, g2, be2);
  #pragma unroll
  for (int q=0;q<16;++q){ float s=b2[q];
    #pragma unroll
    for (int p=0;p<16;++p) s = fmaf(y[p], W2[p*16+q], s);
    v[q]=s; }
  ln_relu16(v, y, g3, be3);
  #pragma unroll
  for (int hh=0;hh<8;++hh){ float s=b3[hh];
    #pragma unroll
    for (int p=0;p<16;++p) s = fmaf(y[p], W3[p*8+hh], s);
    a[hh*LFFT + j] = s; }
}

// ---------- kernel B: forward FFT of a (per head), scrambled order, /L ----------
__global__ __launch_bounds__(NT, 4) void afft_kernel(const float* __restrict__ a,
                                                     float2* __restrict__ Ahat){
  __shared__ float2 z[LFFT];
  __shared__ float2 twHi[128];
  __shared__ float2 twLo[64];
  init_tw(twHi, twLo);
  const int h = blockIdx.x, tid = threadIdx.x;
  const float* ah = a + h*LFFT;
  #pragma unroll
  for (int r = 0; r < LFFT/NT; ++r){
    int j = r*NT + tid;
    z[swz(j)] = make_float2(ah[j], 0.f);
  }
  __syncthreads();
  // radix-2 DIF stage, full length 8192  (swz(4096)=4096)
  #pragma unroll
  for (int r = 0; r < LFFT/2/NT; ++r){
    int i = r*NT + tid;
    int s = swz(i);
    float2 u = z[s], v = z[s ^ 4096];
    z[s]        = cadd(u, v);
    z[s ^ 4096] = cmul(csub(u, v), twget(twHi,twLo,i));
  }
  __syncthreads();
  fwd_r8<512>(z,twHi,twLo); fwd_r8<64>(z,twHi,twLo);
  fwd_r8<8>(z,twHi,twLo);   fwd_r8<1>(z,twHi,twLo);
  const float sc = 1.f/(float)LFFT;
  float2* Ah = Ahat + h*LFFT;
  #pragma unroll
  for (int r = 0; r < LFFT/NT; ++r){
    int p = r*NT + tid;
    float2 v = z[swz(p)];
    Ah[p] = make_float2(v.x*sc, v.y*sc);
  }
}

// ---------- kernel C: packed-pair FFT convolution ----------
// launch_bounds (NT,4): VGPR cap 128; butterfly needs ~64 (caps of 32 spill —
// rounds 3 & 7). fp32 LDS (fp16 LDS regressed — round 8).
__global__ __launch_bounds__(NT, 4) void conv_kernel(const float* __restrict__ x,
                                                     const float2* __restrict__ Ahat,
                                                     float* __restrict__ out){
  __shared__ float2 z[LFFT];
  __shared__ float2 twHi[128];
  __shared__ float2 twLo[64];
  init_tw(twHi, twLo);

  // XCD-aware swizzle: 32 e-pair blocks of the same (b,h) land on one XCD
  int bid = blockIdx.x;                       // 0..2047
  int logical = (bid & 7)*256 + (bid >> 3);
  int bh   = logical >> 5;                    // 0..63  (b*8+h)
  int pair = logical & 31;                    // 0..31
  int h    = bh & 7;
  const int tid = threadIdx.x;

  // load two adjacent e-columns as one complex sequence; fuse first radix-2
  // stage (upper half is zero padding): z[i]=v, z[i+4096]=v*W^i
  const float2* xp = (const float2*)x + (size_t)bh*NSEQ*32 + pair;
  #pragma unroll
  for (int r = 0; r < NSEQ/NT; ++r){
    int s = r*NT + tid;
    float2 v = xp[(size_t)s*32];
    int sw = swz(s);
    z[sw]        = v;
    z[sw ^ 4096] = cmul(v, twget(twHi,twLo,s));
  }
  __syncthreads();

  fwd_r8<512>(z,twHi,twLo); fwd_r8<64>(z,twHi,twLo);
  fwd_r8<8>(z,twHi,twLo);

  // last fwd stage fused with spectrum multiply (scrambled order matches afft)
  fwd_r8_mulA(z, Ahat + h*LFFT);

  inv_r8<1>(z,twHi,twLo);   inv_r8<8>(z,twHi,twLo);
  inv_r8<64>(z,twHi,twLo);  inv_r8<512>(z,twHi,twLo);

  // final inverse radix-2 stage fused with the store (only low half needed)
  float2* op = (float2*)out + (size_t)bh*NSEQ*32 + pair;
  #pragma unroll
  for (int r = 0; r < NSEQ/NT; ++r){
    int i = r*NT + tid;
    int s = swz(i);
    float2 u = z[s];
    float2 v = cmulc(z[s ^ 4096], twget(twHi,twLo,i));
    op[(size_t)i*32] = cadd(u, v);
  }
}

// ---------- launch ----------
extern "C" void kernel_launch(void* const* d_in, const int* in_sizes, int n_in,
                              void* d_out, int out_size, void* d_ws, size_t ws_size,
                              hipStream_t stream){
  const float* x   = (const float*)d_in[0];
  const float* W0  = (const float*)d_in[1];
  const float* b0  = (const float*)d_in[2];
  const float* g1  = (const float*)d_in[3];
  const float* be1 = (const float*)d_in[4];
  const float* W1  = (const float*)d_in[5];
  const float* b1  = (const float*)d_in[6];
  const float* g2  = (const float*)d_in[7];
  const float* be2 = (const float*)d_in[8];
  const float* W2  = (const float*)d_in[9];
  const float* b2  = (const float*)d_in[10];
  const float* g3  = (const float*)d_in[11];
  const float* be3 = (const float*)d_in[12];
  const float* W3  = (const float*)d_in[13];
  const float* b3  = (const float*)d_in[14];

  float*  a    = (float*)d_ws;                                   // 8*8192 f32 = 256 KB
  float2* Ahat = (float2*)((char*)d_ws + (size_t)8*LFFT*sizeof(float)); // 8*8192 c64 = 512 KB
  float*  outp = (float*)d_out;

  dpb_kernel<<<LFFT/256, 256, 0, stream>>>(W0,b0,g1,be1,W1,b1,g2,be2,W2,b2,g3,be3,W3,b3, a);
  afft_kernel<<<8, NT, 0, stream>>>(a, Ahat);
  conv_kernel<<<2048, NT, 0, stream>>>(x, Ahat, outp);
}